// Round 1
// 1595.804 us; speedup vs baseline: 1.0870x; 1.0870x over previous
//
#include <hip/hip_runtime.h>
#include <math.h>

typedef float floatx4 __attribute__((ext_vector_type(4)));
typedef __bf16 bf16x8 __attribute__((ext_vector_type(8)));
typedef unsigned short ushortx8 __attribute__((ext_vector_type(8)));
typedef unsigned short ushortx4 __attribute__((ext_vector_type(4)));
typedef unsigned short ushortx2 __attribute__((ext_vector_type(2)));

typedef unsigned int __attribute__((address_space(1))) as1_uint;
typedef unsigned int __attribute__((address_space(3))) as3_uint;

#define DEV static __device__ __forceinline__

DEV unsigned short f32_bf16(float f) {
  unsigned u = __float_as_uint(f);
  u += 0x7FFFu + ((u >> 16) & 1u);
  return (unsigned short)(u >> 16);
}
DEV float bf16_f32(unsigned short h) { return __uint_as_float(((unsigned)h) << 16); }
DEV float gelu_f(float x) {
  float x3 = x * x * x;
  return 0.5f * x * (1.0f + tanhf(0.79788456080286536f * (x + 0.044715f * x3)));
}
DEV void gload16(const void* g, void* l) {
  __builtin_amdgcn_global_load_lds((const as1_uint*)g, (as3_uint*)l, 16, 0, 0);
}
DEV floatx4 mfma16(ushortx8 a, ushortx8 b, floatx4 c) {
  return __builtin_amdgcn_mfma_f32_16x16x32_bf16(
      __builtin_bit_cast(bf16x8, a), __builtin_bit_cast(bf16x8, b), c, 0, 0, 0);
}

// ---------------- small kernels ----------------

__global__ void zero_f(float* p, int n) {
  int i = threadIdx.x;
  if (i < n) p[i] = 0.f;
}

__global__ void cvt_f32_bf16(const float* __restrict__ in, unsigned short* __restrict__ out,
                             long n4) {
  long i = (long)blockIdx.x * blockDim.x + threadIdx.x;
  if (i >= n4) return;
  float4 v = ((const float4*)in)[i];
  ushortx4 o;
  o.x = f32_bf16(v.x); o.y = f32_bf16(v.y); o.z = f32_bf16(v.z); o.w = f32_bf16(v.w);
  ((ushortx4*)out)[i] = o;
}

// out[n*cw + k] = in[n*8192 + cbase + k], n<2048, k<cw ; cwlog4 = log2(cw/4)
__global__ void cvt_cols(const float* __restrict__ in, unsigned short* __restrict__ out,
                         int cbase, int cwlog4, long n4) {
  long i = (long)blockIdx.x * blockDim.x + threadIdx.x;
  if (i >= n4) return;
  int n = (int)(i >> cwlog4);
  int k4 = (int)(i & ((1 << cwlog4) - 1)) << 2;
  float4 v = *(const float4*)&in[(size_t)n * 8192 + cbase + k4];
  ushortx4 o;
  o.x = f32_bf16(v.x); o.y = f32_bf16(v.y); o.z = f32_bf16(v.z); o.w = f32_bf16(v.w);
  *(ushortx4*)&out[((size_t)n << (cwlog4 + 2)) + k4] = o;
}

// one wave per (bh,d) row of 128; scale by 1/sqrt(S), softmax, bf16 out
__global__ __launch_bounds__(256) void softmax_k(const float* __restrict__ sc,
                                                 unsigned short* __restrict__ probs) {
  int r = blockIdx.x * 4 + (threadIdx.x >> 6);
  int lane = threadIdx.x & 63;
  size_t base = (size_t)(r >> 7) * 16384 + (size_t)(r & 127) * 128;
  int e0 = lane * 2;
  float2 p = *(const float2*)&sc[base + e0];
  const float scale = 0.022097086912079608f;  // 1/sqrt(2048)
  float vx = p.x * scale, vy = p.y * scale;
  float m = fmaxf(vx, vy);
#pragma unroll
  for (int off = 32; off; off >>= 1) m = fmaxf(m, __shfl_xor(m, off));
  float ex = expf(vx - m), ey = expf(vy - m);
  float s = ex + ey;
#pragma unroll
  for (int off = 32; off; off >>= 1) s += __shfl_xor(s, off);
  float inv = 1.f / s;
  ushortx2 o;
  o.x = f32_bf16(ex * inv);
  o.y = f32_bf16(ey * inv);
  *(ushortx2*)&probs[base + e0] = o;
}

// global layernorm apply: out = (r - mean)*rstd*w[col] + b[col]
__global__ void ln_apply(const float* __restrict__ r, const float* __restrict__ stats,
                         const float* __restrict__ w, const float* __restrict__ bia,
                         float* __restrict__ outF, unsigned short* __restrict__ outB, long n4) {
  long i = (long)blockIdx.x * blockDim.x + threadIdx.x;
  if (i >= n4) return;
  const double total = 16777216.0;
  double mean = (double)stats[0] / total;
  double var = ((double)stats[1] - total * mean * mean) / (total - 1.0);
  float rstd = (float)(1.0 / sqrt(var + 1e-12));
  float fm = (float)mean;
  int col = (int)((i * 4) & 2047);
  float4 v = ((const float4*)r)[i];
  float4 wv = *(const float4*)&w[col];
  float4 bv = *(const float4*)&bia[col];
  float4 o;
  o.x = (v.x - fm) * rstd * wv.x + bv.x;
  o.y = (v.y - fm) * rstd * wv.y + bv.y;
  o.z = (v.z - fm) * rstd * wv.z + bv.z;
  o.w = (v.w - fm) * rstd * wv.w + bv.w;
  if (outF) ((float4*)outF)[i] = o;
  if (outB) {
    ushortx4 ob;
    ob.x = f32_bf16(o.x); ob.y = f32_bf16(o.y); ob.z = f32_bf16(o.z); ob.w = f32_bf16(o.w);
    ((ushortx4*)outB)[i] = ob;
  }
}

// ---------------- 128-tile GEMM (kept for scores / PV, z-sliced) ----------------
__global__ __launch_bounds__(256) void gemm_bt(
    const unsigned short* __restrict__ A, int lda, long sAo, long sAi,
    const unsigned short* __restrict__ B, int ldb, long sBo, long sBi,
    int K, int innerCnt,
    const float* __restrict__ bias, const float* __restrict__ residF,
    const unsigned short* __restrict__ residB, int accum,
    float* __restrict__ outF, unsigned short* __restrict__ outB,
    unsigned short* __restrict__ outQT,
    int ldc, long sCo, long sCi, int doGelu, float* __restrict__ stats) {
  __shared__ unsigned short As[128 * 64];
  __shared__ unsigned short Bs[128 * 64];
  const int tid = threadIdx.x;
  const int wave = tid >> 6;
  const int lane = tid & 63;
  const int z = blockIdx.z;
  const int zo = z / innerCnt, zi = z % innerCnt;
  const unsigned short* Ab = A + zo * sAo + zi * sAi;
  const unsigned short* Bb = B + zo * sBo + zi * sBi;
  const long coff = zo * sCo + zi * sCi;
  const int m0 = blockIdx.y * 128;
  const int n0 = blockIdx.x * 128;

  const int quad = lane >> 4;
  const int l16 = lane & 15;
  const int wm = (wave & 1) * 64;
  const int wn = (wave >> 1) * 64;
  const int srow = lane >> 3;
  const int kofs8 = (((lane & 7) ^ srow) & 7) * 8;

  floatx4 acc[4][4];
#pragma unroll
  for (int i = 0; i < 4; i++)
#pragma unroll
    for (int j = 0; j < 4; j++) acc[i][j] = (floatx4){0.f, 0.f, 0.f, 0.f};

  const int nK = K >> 6;
  for (int kt = 0; kt < nK; ++kt) {
    const int k0 = kt << 6;
    __syncthreads();
#pragma unroll
    for (int i = 0; i < 4; ++i) {
      const int rb = wave * 32 + i * 8;
      gload16(Ab + (size_t)(m0 + rb + srow) * lda + k0 + kofs8, &As[rb * 64]);
      gload16(Bb + (size_t)(n0 + rb + srow) * ldb + k0 + kofs8, &Bs[rb * 64]);
    }
    __syncthreads();
#pragma unroll
    for (int kk = 0; kk < 2; ++kk) {
      ushortx8 af[4], bf[4];
      const int swz = (l16 & 7);
#pragma unroll
      for (int i = 0; i < 4; i++)
        af[i] = *(const ushortx8*)&As[(wm + i * 16 + l16) * 64 +
                                      (((kk * 4 + quad) ^ swz) * 8)];
#pragma unroll
      for (int j = 0; j < 4; j++)
        bf[j] = *(const ushortx8*)&Bs[(wn + j * 16 + l16) * 64 +
                                      (((kk * 4 + quad) ^ swz) * 8)];
#pragma unroll
      for (int i = 0; i < 4; i++)
#pragma unroll
        for (int j = 0; j < 4; j++) acc[i][j] = mfma16(af[i], bf[j], acc[i][j]);
    }
  }

  float s1 = 0.f, s2 = 0.f;
#pragma unroll
  for (int i = 0; i < 4; i++) {
#pragma unroll
    for (int j = 0; j < 4; j++) {
      const int col = n0 + wn + j * 16 + l16;
      const float bv = bias ? bias[col] : 0.f;
#pragma unroll
      for (int r = 0; r < 4; r++) {
        const int row = m0 + wm + i * 16 + quad * 4 + r;
        float v = acc[i][j][r] + bv;
        if (doGelu) v = gelu_f(v);
        if (outQT) {
          const int b = row >> 11, s = row & 2047;
          if (col < 4096) {
            unsigned short* tb = outQT + ((col & 2048) ? 16777216u : 0u);
            const int cc = col & 2047;
            tb[((size_t)((b << 4) + (cc >> 7)) * 128 + (cc & 127)) * 2048 + s] = f32_bf16(v);
          } else {
            outB[(size_t)row * 2048 + (col - 4096)] = f32_bf16(v);
          }
          continue;
        }
        const size_t cidx = (size_t)coff + (size_t)row * ldc + col;
        if (residF) v += residF[cidx];
        if (residB) v += bf16_f32(residB[cidx]);
        if (accum) v += outF[cidx];
        if (outF) outF[cidx] = v;
        else outB[cidx] = f32_bf16(v);
        if (stats) { s1 += v; s2 += v * v; }
      }
    }
  }
  if (stats) {
#pragma unroll
    for (int off = 32; off; off >>= 1) {
      s1 += __shfl_down(s1, off);
      s2 += __shfl_down(s2, off);
    }
    if (lane == 0) {
      atomicAdd(&stats[0], s1);
      atomicAdd(&stats[1], s2);
    }
  }
}

// ---------------- 256x256 8-phase GEMM (T1+T2+T3+T4+T5) ----------------
// C[M,N] = A[M,K] @ B[N,K]^T, fused epilogue identical to gemm_bt (z=1 only).
// 512 thr = 8 waves (2Mx4N), per-wave 128x64 out, BK=64, LDS 128KiB (2 bufs x
// (A 256x64 + B 256x64) bf16, XOR-swizzled 16B slots: phys = logical ^ (row&7)).
// Per phase: {ds_read subtile; stage ONE 16KB slot (2 x global_load_lds x16B);
// s_barrier; lgkmcnt(0); setprio(1); 16 MFMA; setprio(0); [vmcnt(6) at phases
// 4/8]; s_barrier}. Counted vmcnt keeps 3 slots (6 loads) in flight across
// barriers -- never drains in the main loop. Stage slots target regions whose
// last ds_read was >=1 full barrier earlier (slot2=A[0:64)+[128:192) read in
// read-phases 1-2, staged at read-phase 4; slot3 staged after the tile's last
// phase) -- race-free by construction. Requires K%128==0, M%256==0, N%256==0.
__global__ __launch_bounds__(512, 2) void gemm256(
    const unsigned short* __restrict__ A, int lda,
    const unsigned short* __restrict__ B, int ldb, int K,
    const float* __restrict__ bias, const float* __restrict__ residF,
    const unsigned short* __restrict__ residB, int accum,
    float* __restrict__ outF, unsigned short* __restrict__ outB,
    unsigned short* __restrict__ outQT, int ldc, int doGelu,
    float* __restrict__ stats) {
  __shared__ unsigned short As[2][256 * 64];
  __shared__ unsigned short Bs[2][256 * 64];
  const int tid = threadIdx.x;
  const int wave = tid >> 6;     // 0..7
  const int lane = tid & 63;
  const int wm = wave >> 2;      // 0..1  (M)
  const int wn = wave & 3;       // 0..3  (N)
  const int quad = lane >> 4;
  const int l16 = lane & 15;
  const int swz = l16 & 7;

  // bijective XCD-chunked swizzle (m204): each XCD gets a contiguous wgid span
  const int nwg = gridDim.x * gridDim.y;
  const int orig = blockIdx.y * gridDim.x + blockIdx.x;
  const int q8 = nwg >> 3, r8 = nwg & 7;
  const int xcd = orig & 7, lid = orig >> 3;
  const int wgid = (xcd < r8 ? xcd * (q8 + 1) : r8 * (q8 + 1) + (xcd - r8) * q8) + lid;
  const int m0 = (wgid / gridDim.x) * 256;
  const int n0 = (wgid % gridDim.x) * 256;

  const int srow = lane >> 3;
  const int kof = (((lane & 7) ^ srow) & 7) << 3;  // pre-swizzled global k-offset
  const int nkt = K >> 6;                          // even, >= 2

  floatx4 acc[8][4];
#pragma unroll
  for (int i = 0; i < 8; i++)
#pragma unroll
    for (int j = 0; j < 4; j++) acc[i][j] = (floatx4){0.f, 0.f, 0.f, 0.f};

  // stage one 16KB slot of K-tile kt into buf kt&1 (2 gload16/thread).
  // slot 0: B rows [0,128)  slot 1: B rows [128,256)
  // slot 2: A rows [0,64)+[128,192)  slot 3: A rows [64,128)+[192,256)
  auto slot = [&](int kt, int s) {
    const int buf = kt & 1;
    const int k0 = kt << 6;
    if (s < 2) {
      const int rb = s * 128 + wave * 16;
      gload16(B + (size_t)(n0 + rb + srow) * ldb + k0 + kof, &Bs[buf][rb * 64]);
      gload16(B + (size_t)(n0 + rb + 8 + srow) * ldb + k0 + kof, &Bs[buf][(rb + 8) * 64]);
    } else {
      const int rb = ((wave & 4) << 5) + ((wave & 3) << 4) + (s == 3 ? 64 : 0);
      gload16(A + (size_t)(m0 + rb + srow) * lda + k0 + kof, &As[buf][rb * 64]);
      gload16(A + (size_t)(m0 + rb + 8 + srow) * lda + k0 + kof, &As[buf][(rb + 8) * 64]);
    }
  };

  // prologue: tile0 fully + tile1 slots 0-2  (7 slots = 14 loads in flight)
  slot(0, 0); slot(0, 1); slot(0, 2); slot(0, 3);
  if (nkt > 1) { slot(1, 0); slot(1, 1); slot(1, 2); }
  asm volatile("s_waitcnt vmcnt(6)" ::: "memory");  // tile0 landed, 3 slots in flight
  __builtin_amdgcn_s_barrier();
  asm volatile("" ::: "memory");

  ushortx8 bfr[4][2], afr[2][2];
  const int aBase = (wm * 128 + l16) * 64;
  const int bBase = (wn * 64 + l16) * 64;
  const int kq0 = (quad ^ swz) << 3;
  const int kq1 = ((4 + quad) ^ swz) << 3;

  for (int kt = 0; kt < nkt; kt += 2) {
#pragma unroll
    for (int half = 0; half < 2; half++) {
      const unsigned short* Asb = &As[half][0];
      const unsigned short* Bsb = &Bs[half][0];
#pragma unroll
      for (int p = 0; p < 4; p++) {
        // ds_read register subtile (12 reads at p==0, else 4)
        if (p == 0) {
#pragma unroll
          for (int fj = 0; fj < 4; fj++) {
            bfr[fj][0] = *(const ushortx8*)&Bsb[bBase + fj * 1024 + kq0];
            bfr[fj][1] = *(const ushortx8*)&Bsb[bBase + fj * 1024 + kq1];
          }
        }
#pragma unroll
        for (int fi = 0; fi < 2; fi++) {
          afr[fi][0] = *(const ushortx8*)&Asb[aBase + (p * 2 + fi) * 1024 + kq0];
          afr[fi][1] = *(const ushortx8*)&Asb[aBase + (p * 2 + fi) * 1024 + kq1];
        }
        // stage one slot (issue-ahead; lands under later phases' MFMA)
        if (half == 0) {
          if (p == 0) { if (kt + 1 < nkt) slot(kt + 1, 3); }
          else { if (kt + 2 < nkt) slot(kt + 2, p - 1); }
        } else {
          if (p == 0) { if (kt + 2 < nkt) slot(kt + 2, 3); }
          else { if (kt + 3 < nkt) slot(kt + 3, p - 1); }
        }
        __builtin_amdgcn_s_barrier();
        asm volatile("s_waitcnt lgkmcnt(0)" ::: "memory");
        __builtin_amdgcn_s_setprio(1);
#pragma unroll
        for (int fi = 0; fi < 2; fi++)
#pragma unroll
          for (int fj = 0; fj < 4; fj++) {
            acc[p * 2 + fi][fj] = mfma16(afr[fi][0], bfr[fj][0], acc[p * 2 + fi][fj]);
            acc[p * 2 + fi][fj] = mfma16(afr[fi][1], bfr[fj][1], acc[p * 2 + fi][fj]);
          }
        __builtin_amdgcn_s_setprio(0);
        if (p == 3) {
          const bool more = (half == 0) ? (kt + 2 < nkt) : (kt + 3 < nkt);
          if (more) asm volatile("s_waitcnt vmcnt(6)" ::: "memory");
          else asm volatile("s_waitcnt vmcnt(0)" ::: "memory");
        }
        __builtin_amdgcn_s_barrier();
        asm volatile("" ::: "memory");
      }
    }
  }

  // epilogue (same semantics as gemm_bt, z=1)
  float s1 = 0.f, s2 = 0.f;
#pragma unroll
  for (int i = 0; i < 8; i++) {
#pragma unroll
    for (int j = 0; j < 4; j++) {
      const int col = n0 + wn * 64 + j * 16 + l16;
      const float bv = bias ? bias[col] : 0.f;
#pragma unroll
      for (int r = 0; r < 4; r++) {
        const int row = m0 + wm * 128 + i * 16 + quad * 4 + r;
        float v = acc[i][j][r] + bv;
        if (doGelu) v = gelu_f(v);
        if (outQT) {
          const int b = row >> 11, s = row & 2047;
          if (col < 4096) {
            unsigned short* tb = outQT + ((col & 2048) ? 16777216u : 0u);
            const int cc = col & 2047;
            tb[((size_t)((b << 4) + (cc >> 7)) * 128 + (cc & 127)) * 2048 + s] = f32_bf16(v);
          } else {
            outB[(size_t)row * 2048 + (col - 4096)] = f32_bf16(v);
          }
          continue;
        }
        const size_t cidx = (size_t)row * ldc + col;
        if (residF) v += residF[cidx];
        if (residB) v += bf16_f32(residB[cidx]);
        if (accum) v += outF[cidx];
        if (outF) outF[cidx] = v;
        else outB[cidx] = f32_bf16(v);
        if (stats) { s1 += v; s2 += v * v; }
      }
    }
  }
  if (stats) {
#pragma unroll
    for (int off = 32; off; off >>= 1) {
      s1 += __shfl_down(s1, off);
      s2 += __shfl_down(s2, off);
    }
    if (lane == 0) {
      atomicAdd(&stats[0], s1);
      atomicAdd(&stats[1], s2);
    }
  }
}

// ---------------- launch ----------------
// Workspace (region lifetimes overlapped), base 152 MiB:
//   P0 32MiB: xbf -> attnbf -> hchunk(nc=4)
//   P1 24MiB: W1bf -> {spart(4)+probs(2)} -> W2bf(8) -> {fc_ch(8)+pj_ch(8)} (nc=4)
//   P2 96MiB: {vbf(32)+qT(32)+kT(32)} -> {r12 fp32(64) + x1bf(32)}
//   P3 (optional, ws-adaptive): FFN fc/pj/h for nc=1 (192MiB) or nc=2 (96MiB)

extern "C" void kernel_launch(void* const* d_in, const int* in_sizes, int n_in, void* d_out,
                              int out_size, void* d_ws, size_t ws_size, hipStream_t stream) {
  (void)in_sizes; (void)n_in; (void)out_size;
  const float* x    = (const float*)d_in[0];
  const float* W1w  = (const float*)d_in[1];
  const float* W1b  = (const float*)d_in[2];
  const float* W2w  = (const float*)d_in[3];
  const float* W2b  = (const float*)d_in[4];
  const float* fcw  = (const float*)d_in[5];
  const float* fcb  = (const float*)d_in[6];
  const float* pjw  = (const float*)d_in[7];
  const float* pjb  = (const float*)d_in[8];
  const float* ln1w = (const float*)d_in[9];
  const float* ln1b = (const float*)d_in[10];
  const float* ln2w = (const float*)d_in[11];
  const float* ln2b = (const float*)d_in[12];
  float* out = (float*)d_out;

  char* ws = (char*)d_ws;
  size_t off = 0;
  auto take = [&](size_t b) { size_t r = off; off = (off + b + 255) & ~(size_t)255; return r; };
  float* stats = (float*)(ws + take(256));
  size_t P0 = take(33554432);
  size_t P1 = take(25165824);
  size_t P2 = take(100663296);
  size_t P3 = off;

  unsigned short* xbf    = (unsigned short*)(ws + P0);
  unsigned short* attnbf = (unsigned short*)(ws + P0);
  unsigned short* W1bf   = (unsigned short*)(ws + P1);
  float*          spart  = (float*)(ws + P1);
  unsigned short* probs  = (unsigned short*)(ws + P1 + 4194304);
  unsigned short* W2bf   = (unsigned short*)(ws + P1);
  unsigned short* vbf    = (unsigned short*)(ws + P2);
  unsigned short* qT     = (unsigned short*)(ws + P2 + 33554432);  // kT = qT + 16Mi elems
  float*          r12    = (float*)(ws + P2);
  unsigned short* x1bf   = (unsigned short*)(ws + P2 + 67108864);

  // ws-adaptive FFN chunking
  int nc;
  unsigned short *fc_ch, *pj_ch, *hch;
  if (ws_size >= P3 + 201326592) {  // 192 MiB extra
    nc = 1;
    fc_ch = (unsigned short*)(ws + P3);
    pj_ch = (unsigned short*)(ws + P3 + 33554432);
    hch   = (unsigned short*)(ws + P3 + 67108864);
  } else if (ws_size >= P3 + 100663296) {  // 96 MiB extra
    nc = 2;
    fc_ch = (unsigned short*)(ws + P3);
    pj_ch = (unsigned short*)(ws + P3 + 16777216);
    hch   = (unsigned short*)(ws + P3 + 33554432);
  } else {
    nc = 4;
    fc_ch = (unsigned short*)(ws + P1);
    pj_ch = (unsigned short*)(ws + P1 + 8388608);
    hch   = (unsigned short*)(ws + P0);
  }
  const int cw = 8192 / nc;
  const int cwlog4 = (nc == 1) ? 11 : (nc == 2) ? 10 : 9;
  const long cn4 = (long)cw << 9;  // cw*2048/4

  zero_f<<<1, 64, 0, stream>>>(stats, 16);
  cvt_f32_bf16<<<16384, 256, 0, stream>>>(x, xbf, 4194304);
  cvt_f32_bf16<<<12288, 256, 0, stream>>>(W1w, W1bf, 3145728);

  // QKV: [8192,2048] @ [6144,2048]^T + W1_b -> qT/kT [b,h,128,2048] + vbf [8192,2048]
  gemm256<<<dim3(24, 32, 1), 512, 0, stream>>>(xbf, 2048, W1bf, 2048, 2048, W1b, nullptr,
                                               nullptr, 0, nullptr, vbf, qT, 0, 0, nullptr);
  // scores per (b,h): qT[128,2048] @ kT[128,2048]^T -> spart [bh][128][128] fp32
  gemm_bt<<<dim3(1, 1, 64), 256, 0, stream>>>(qT, 2048, 0, 262144L, qT + 16777216, 2048, 0,
                                              262144L, 2048, 64, nullptr, nullptr, nullptr, 0,
                                              spart, nullptr, nullptr, 128, 0, 16384L, 0, nullptr);
  softmax_k<<<2048, 256, 0, stream>>>(spart, probs);
  // PV per (b,h): P[128,128] @ V[2048,128]^T -> attn2d[b, h*128+d, s] bf16
  gemm_bt<<<dim3(16, 1, 64), 256, 0, stream>>>(probs, 128, 262144L, 16384L, vbf, 2048, 4194304L,
                                               128L, 128, 16, nullptr, nullptr, nullptr, 0,
                                               nullptr, attnbf, nullptr, 2048, 4194304L, 262144L,
                                               0, nullptr);
  cvt_f32_bf16<<<4096, 256, 0, stream>>>(W2w, W2bf, 1048576);
  // W2 + bias + residual(x fp32) -> r1 fp32, stats[0:2]
  gemm256<<<dim3(8, 32, 1), 512, 0, stream>>>(attnbf, 2048, W2bf, 2048, 2048, W2b, x, nullptr,
                                              0, r12, nullptr, nullptr, 2048, 0, stats);
  ln_apply<<<16384, 256, 0, stream>>>(r12, stats, ln1w, ln1b, nullptr, x1bf, 4194304);

  // FFN in nc chunks of cw: h = gelu(x1 @ fc_ch^T + fcb_ch); r2 (+)= h @ pj_ch^T
  for (int c = 0; c < nc; ++c) {
    cvt_f32_bf16<<<(int)(cn4 / 256), 256, 0, stream>>>(fcw + (size_t)c * cw * 2048, fc_ch, cn4);
    cvt_cols<<<(int)(cn4 / 256), 256, 0, stream>>>(pjw, pj_ch, c * cw, cwlog4, cn4);
    gemm256<<<dim3(cw / 256, 32, 1), 512, 0, stream>>>(x1bf, 2048, fc_ch, 2048, 2048,
                                                       fcb + c * cw, nullptr, nullptr, 0,
                                                       nullptr, hch, nullptr, cw, 1, nullptr);
    const int last = (c == nc - 1);
    gemm256<<<dim3(8, 32, 1), 512, 0, stream>>>(hch, cw, pj_ch, cw, cw,
                                                last ? pjb : nullptr, nullptr,
                                                last ? x1bf : nullptr, c > 0, r12, nullptr,
                                                nullptr, 2048, 0,
                                                last ? (stats + 2) : nullptr);
  }
  ln_apply<<<16384, 256, 0, stream>>>(r12, stats + 2, ln2w, ln2b, out, nullptr, 4194304);
}

// Round 2
// 1345.524 us; speedup vs baseline: 1.2892x; 1.1860x over previous
//
#include <hip/hip_runtime.h>
#include <math.h>

typedef float floatx4 __attribute__((ext_vector_type(4)));
typedef __bf16 bf16x8 __attribute__((ext_vector_type(8)));
typedef unsigned short ushortx8 __attribute__((ext_vector_type(8)));
typedef unsigned short ushortx4 __attribute__((ext_vector_type(4)));
typedef unsigned short ushortx2 __attribute__((ext_vector_type(2)));

typedef unsigned int __attribute__((address_space(1))) as1_uint;
typedef unsigned int __attribute__((address_space(3))) as3_uint;

#define DEV static __device__ __forceinline__

DEV unsigned short f32_bf16(float f) {
  unsigned u = __float_as_uint(f);
  u += 0x7FFFu + ((u >> 16) & 1u);
  return (unsigned short)(u >> 16);
}
DEV float bf16_f32(unsigned short h) { return __uint_as_float(((unsigned)h) << 16); }
DEV float gelu_f(float x) {
  // 0.5x(1+tanh(t)) == x * sigmoid(2t); error vs tanhf ~1e-7 rel, << bf16 ulp
  float t2 = 1.5957691216057308f * (x + 0.044715f * x * x * x);
  return x * __builtin_amdgcn_rcpf(1.0f + __expf(-t2));
}
DEV void gload16(const void* g, void* l) {
  __builtin_amdgcn_global_load_lds((const as1_uint*)g, (as3_uint*)l, 16, 0, 0);
}
DEV floatx4 mfma16(ushortx8 a, ushortx8 b, floatx4 c) {
  return __builtin_amdgcn_mfma_f32_16x16x32_bf16(
      __builtin_bit_cast(bf16x8, a), __builtin_bit_cast(bf16x8, b), c, 0, 0, 0);
}

// ---------------- small kernels ----------------

__global__ void zero_f(float* p, int n) {
  int i = threadIdx.x;
  if (i < n) p[i] = 0.f;
}

__global__ void cvt_f32_bf16(const float* __restrict__ in, unsigned short* __restrict__ out,
                             long n4) {
  long i = (long)blockIdx.x * blockDim.x + threadIdx.x;
  if (i >= n4) return;
  float4 v = ((const float4*)in)[i];
  ushortx4 o;
  o.x = f32_bf16(v.x); o.y = f32_bf16(v.y); o.z = f32_bf16(v.z); o.w = f32_bf16(v.w);
  ((ushortx4*)out)[i] = o;
}

// out[n*cw + k] = in[n*8192 + cbase + k], n<2048, k<cw ; cwlog4 = log2(cw/4)
__global__ void cvt_cols(const float* __restrict__ in, unsigned short* __restrict__ out,
                         int cbase, int cwlog4, long n4) {
  long i = (long)blockIdx.x * blockDim.x + threadIdx.x;
  if (i >= n4) return;
  int n = (int)(i >> cwlog4);
  int k4 = (int)(i & ((1 << cwlog4) - 1)) << 2;
  float4 v = *(const float4*)&in[(size_t)n * 8192 + cbase + k4];
  ushortx4 o;
  o.x = f32_bf16(v.x); o.y = f32_bf16(v.y); o.z = f32_bf16(v.z); o.w = f32_bf16(v.w);
  *(ushortx4*)&out[((size_t)n << (cwlog4 + 2)) + k4] = o;
}

// one wave per (bh,d) row of 128; sums 4 K-split partials (stride 1Mi floats),
// scale by 1/sqrt(S), softmax, bf16 out
__global__ __launch_bounds__(256) void softmax_k(const float* __restrict__ sc,
                                                 unsigned short* __restrict__ probs) {
  int r = blockIdx.x * 4 + (threadIdx.x >> 6);
  int lane = threadIdx.x & 63;
  size_t base = (size_t)(r >> 7) * 16384 + (size_t)(r & 127) * 128 + lane * 2;
  float2 p0 = *(const float2*)&sc[base];
  float2 p1 = *(const float2*)&sc[base + 1048576];
  float2 p2 = *(const float2*)&sc[base + 2097152];
  float2 p3 = *(const float2*)&sc[base + 3145728];
  const float scale = 0.022097086912079608f;  // 1/sqrt(2048)
  float vx = (p0.x + p1.x + p2.x + p3.x) * scale;
  float vy = (p0.y + p1.y + p2.y + p3.y) * scale;
  float m = fmaxf(vx, vy);
#pragma unroll
  for (int off = 32; off; off >>= 1) m = fmaxf(m, __shfl_xor(m, off));
  float ex = expf(vx - m), ey = expf(vy - m);
  float s = ex + ey;
#pragma unroll
  for (int off = 32; off; off >>= 1) s += __shfl_xor(s, off);
  float inv = 1.f / s;
  ushortx2 o;
  o.x = f32_bf16(ex * inv);
  o.y = f32_bf16(ey * inv);
  *(ushortx2*)&probs[base] = o;
}

// global layernorm apply: out = (r - mean)*rstd*w[col] + b[col]
__global__ void ln_apply(const float* __restrict__ r, const float* __restrict__ stats,
                         const float* __restrict__ w, const float* __restrict__ bia,
                         float* __restrict__ outF, unsigned short* __restrict__ outB, long n4) {
  long i = (long)blockIdx.x * blockDim.x + threadIdx.x;
  if (i >= n4) return;
  const double total = 16777216.0;
  double mean = (double)stats[0] / total;
  double var = ((double)stats[1] - total * mean * mean) / (total - 1.0);
  float rstd = (float)(1.0 / sqrt(var + 1e-12));
  float fm = (float)mean;
  int col = (int)((i * 4) & 2047);
  float4 v = ((const float4*)r)[i];
  float4 wv = *(const float4*)&w[col];
  float4 bv = *(const float4*)&bia[col];
  float4 o;
  o.x = (v.x - fm) * rstd * wv.x + bv.x;
  o.y = (v.y - fm) * rstd * wv.y + bv.y;
  o.z = (v.z - fm) * rstd * wv.z + bv.z;
  o.w = (v.w - fm) * rstd * wv.w + bv.w;
  if (outF) ((float4*)outF)[i] = o;
  if (outB) {
    ushortx4 ob;
    ob.x = f32_bf16(o.x); ob.y = f32_bf16(o.y); ob.z = f32_bf16(o.z); ob.w = f32_bf16(o.w);
    ((ushortx4*)outB)[i] = ob;
  }
}

// ---------------- 128-tile GEMM (kept for scores / PV, z-sliced) ----------------
__global__ __launch_bounds__(256) void gemm_bt(
    const unsigned short* __restrict__ A, int lda, long sAo, long sAi,
    const unsigned short* __restrict__ B, int ldb, long sBo, long sBi,
    int K, int innerCnt,
    const float* __restrict__ bias, const float* __restrict__ residF,
    const unsigned short* __restrict__ residB, int accum,
    float* __restrict__ outF, unsigned short* __restrict__ outB,
    unsigned short* __restrict__ outQT,
    int ldc, long sCo, long sCi, int doGelu, float* __restrict__ stats) {
  __shared__ unsigned short As[128 * 64];
  __shared__ unsigned short Bs[128 * 64];
  const int tid = threadIdx.x;
  const int wave = tid >> 6;
  const int lane = tid & 63;
  const int z = blockIdx.z;
  const int zo = z / innerCnt, zi = z % innerCnt;
  const unsigned short* Ab = A + zo * sAo + zi * sAi;
  const unsigned short* Bb = B + zo * sBo + zi * sBi;
  const long coff = zo * sCo + zi * sCi;
  const int m0 = blockIdx.y * 128;
  const int n0 = blockIdx.x * 128;

  const int quad = lane >> 4;
  const int l16 = lane & 15;
  const int wm = (wave & 1) * 64;
  const int wn = (wave >> 1) * 64;
  const int srow = lane >> 3;
  const int kofs8 = (((lane & 7) ^ srow) & 7) * 8;

  floatx4 acc[4][4];
#pragma unroll
  for (int i = 0; i < 4; i++)
#pragma unroll
    for (int j = 0; j < 4; j++) acc[i][j] = (floatx4){0.f, 0.f, 0.f, 0.f};

  const int nK = K >> 6;
  for (int kt = 0; kt < nK; ++kt) {
    const int k0 = kt << 6;
    __syncthreads();
#pragma unroll
    for (int i = 0; i < 4; ++i) {
      const int rb = wave * 32 + i * 8;
      gload16(Ab + (size_t)(m0 + rb + srow) * lda + k0 + kofs8, &As[rb * 64]);
      gload16(Bb + (size_t)(n0 + rb + srow) * ldb + k0 + kofs8, &Bs[rb * 64]);
    }
    __syncthreads();
#pragma unroll
    for (int kk = 0; kk < 2; ++kk) {
      ushortx8 af[4], bf[4];
      const int swz = (l16 & 7);
#pragma unroll
      for (int i = 0; i < 4; i++)
        af[i] = *(const ushortx8*)&As[(wm + i * 16 + l16) * 64 +
                                      (((kk * 4 + quad) ^ swz) * 8)];
#pragma unroll
      for (int j = 0; j < 4; j++)
        bf[j] = *(const ushortx8*)&Bs[(wn + j * 16 + l16) * 64 +
                                      (((kk * 4 + quad) ^ swz) * 8)];
#pragma unroll
      for (int i = 0; i < 4; i++)
#pragma unroll
        for (int j = 0; j < 4; j++) acc[i][j] = mfma16(af[i], bf[j], acc[i][j]);
    }
  }

  float s1 = 0.f, s2 = 0.f;
#pragma unroll
  for (int i = 0; i < 4; i++) {
#pragma unroll
    for (int j = 0; j < 4; j++) {
      const int col = n0 + wn + j * 16 + l16;
      const float bv = bias ? bias[col] : 0.f;
#pragma unroll
      for (int r = 0; r < 4; r++) {
        const int row = m0 + wm + i * 16 + quad * 4 + r;
        float v = acc[i][j][r] + bv;
        if (doGelu) v = gelu_f(v);
        if (outQT) {
          const int b = row >> 11, s = row & 2047;
          if (col < 4096) {
            unsigned short* tb = outQT + ((col & 2048) ? 16777216u : 0u);
            const int cc = col & 2047;
            tb[((size_t)((b << 4) + (cc >> 7)) * 128 + (cc & 127)) * 2048 + s] = f32_bf16(v);
          } else {
            outB[(size_t)row * 2048 + (col - 4096)] = f32_bf16(v);
          }
          continue;
        }
        const size_t cidx = (size_t)coff + (size_t)row * ldc + col;
        if (residF) v += residF[cidx];
        if (residB) v += bf16_f32(residB[cidx]);
        if (accum) v += outF[cidx];
        if (outF) outF[cidx] = v;
        else outB[cidx] = f32_bf16(v);
        if (stats) { s1 += v; s2 += v * v; }
      }
    }
  }
  if (stats) {
#pragma unroll
    for (int off = 32; off; off >>= 1) {
      s1 += __shfl_down(s1, off);
      s2 += __shfl_down(s2, off);
    }
    if (lane == 0) {
      atomicAdd(&stats[0], s1);
      atomicAdd(&stats[1], s2);
    }
  }
}

// ---------------- 256x256 8-phase GEMM (T1+T2+T3+T4+T5) ----------------
// Round-2 changes vs round-1:
//  * derived per-slot vmcnt waits (p1: vmcnt(10), p3: vmcnt(8); tail 8/2/0/0)
//    -- every staged slot now has >=4 phases of latency cover; never drains
//    to 0 in the main loop. Simulated: forces exactly the slots whose data
//    is read in the next two phases.
//  * dropped forced lgkmcnt(0): ds_reads are plain C++ loads, the compiler
//    emits minimal partial lgkm waits inside the MFMA cluster.
//  * rectangular intra-XCD tiling (8-wide n groups, requires gridDim.x%8==0):
//    concurrent per-XCD panel working set 26MB->12MB.
//  * qT/kT epilogue: per-wave LDS transpose bounce (wave-private 16KB, XOR
//    8B-slot swizzle), 16B fully-coalesced stores instead of 128 scalar
//    2B scatter stores per thread (round-1 QKV: WRITE 272MB vs 96 useful).
__global__ __launch_bounds__(512, 2) void gemm256(
    const unsigned short* __restrict__ A, int lda,
    const unsigned short* __restrict__ B, int ldb, int K,
    const float* __restrict__ bias, const float* __restrict__ residF,
    const unsigned short* __restrict__ residB, int accum,
    float* __restrict__ outF, unsigned short* __restrict__ outB,
    unsigned short* __restrict__ outQT, int ldc, int doGelu,
    float* __restrict__ stats) {
  __shared__ unsigned short As[2][256 * 64];
  __shared__ unsigned short Bs[2][256 * 64];
  const int tid = threadIdx.x;
  const int wave = tid >> 6;     // 0..7
  const int lane = tid & 63;
  const int wm = wave >> 2;      // 0..1  (M)
  const int wn = wave & 3;       // 0..3  (N)
  const int quad = lane >> 4;
  const int l16 = lane & 15;
  const int swz = l16 & 7;

  // bijective XCD-chunked swizzle (m204) + rectangular intra-XCD mapping
  const int nwg = gridDim.x * gridDim.y;
  const int orig = blockIdx.y * gridDim.x + blockIdx.x;
  const int q8 = nwg >> 3, r8 = nwg & 7;
  const int xcd = orig & 7, lid = orig >> 3;
  const int wgid = (xcd < r8 ? xcd * (q8 + 1) : r8 * (q8 + 1) + (xcd - r8) * q8) + lid;
  int m0, n0;
  if ((gridDim.x & 7) == 0) {
    const int gper = (int)(gridDim.y << 3);
    m0 = ((wgid % gper) >> 3) * 256;
    n0 = (((wgid / gper) << 3) + (wgid & 7)) * 256;
  } else {
    m0 = (wgid / gridDim.x) * 256;
    n0 = (wgid % gridDim.x) * 256;
  }

  const int srow = lane >> 3;
  const int kof = (((lane & 7) ^ srow) & 7) << 3;  // pre-swizzled global k-offset
  const int nkt = K >> 6;                          // even, >= 2

  floatx4 acc[8][4];
#pragma unroll
  for (int i = 0; i < 8; i++)
#pragma unroll
    for (int j = 0; j < 4; j++) acc[i][j] = (floatx4){0.f, 0.f, 0.f, 0.f};

  // stage one 16KB slot of K-tile kt into buf kt&1 (2 gload16/thread).
  // slot 0: B rows [0,128)  slot 1: B rows [128,256)
  // slot 2: A rows [0,64)+[128,192)  slot 3: A rows [64,128)+[192,256)
  auto slot = [&](int kt, int s) {
    const int buf = kt & 1;
    const int k0 = kt << 6;
    if (s < 2) {
      const int rb = s * 128 + wave * 16;
      gload16(B + (size_t)(n0 + rb + srow) * ldb + k0 + kof, &Bs[buf][rb * 64]);
      gload16(B + (size_t)(n0 + rb + 8 + srow) * ldb + k0 + kof, &Bs[buf][(rb + 8) * 64]);
    } else {
      const int rb = ((wave & 4) << 5) + ((wave & 3) << 4) + (s == 3 ? 64 : 0);
      gload16(A + (size_t)(m0 + rb + srow) * lda + k0 + kof, &As[buf][rb * 64]);
      gload16(A + (size_t)(m0 + rb + 8 + srow) * lda + k0 + kof, &As[buf][(rb + 8) * 64]);
    }
  };

  // prologue: tile0 fully + tile1 slots 0-2 (7 slots = 14 loads in flight)
  slot(0, 0); slot(0, 1); slot(0, 2); slot(0, 3);
  if (nkt > 1) { slot(1, 0); slot(1, 1); slot(1, 2); }
  asm volatile("s_waitcnt vmcnt(6)" ::: "memory");  // tile0 landed, 3 slots in flight
  __builtin_amdgcn_s_barrier();
  asm volatile("" ::: "memory");

  ushortx8 bfr[4][2], afr[2][2];
  const int aBase = (wm * 128 + l16) * 64;
  const int bBase = (wn * 64 + l16) * 64;
  const int kq0 = (quad ^ swz) << 3;
  const int kq1 = ((4 + quad) ^ swz) << 3;

  for (int kt = 0; kt < nkt; kt += 2) {
    const int m2 = (kt + 2 < nkt);
    const int m3 = (kt + 3 < nkt);
#pragma unroll
    for (int half = 0; half < 2; half++) {
      const unsigned short* Asb = &As[half][0];
      const unsigned short* Bsb = &Bs[half][0];
#pragma unroll
      for (int p = 0; p < 4; p++) {
        // ds_read register subtile (12 reads at p==0, else 4)
        if (p == 0) {
#pragma unroll
          for (int fj = 0; fj < 4; fj++) {
            bfr[fj][0] = *(const ushortx8*)&Bsb[bBase + fj * 1024 + kq0];
            bfr[fj][1] = *(const ushortx8*)&Bsb[bBase + fj * 1024 + kq1];
          }
        }
#pragma unroll
        for (int fi = 0; fi < 2; fi++) {
          afr[fi][0] = *(const ushortx8*)&Asb[aBase + (p * 2 + fi) * 1024 + kq0];
          afr[fi][1] = *(const ushortx8*)&Asb[aBase + (p * 2 + fi) * 1024 + kq1];
        }
        // stage one slot (issue-ahead; lands under later phases' MFMA)
        if (half == 0) {
          if (p == 0) { if (kt + 1 < nkt) slot(kt + 1, 3); }
          else if (m2) slot(kt + 2, p - 1);
        } else {
          if (p == 0) { if (m2) slot(kt + 2, 3); }
          else if (m3) slot(kt + 3, p - 1);
        }
        asm volatile("" ::: "memory");
        __builtin_amdgcn_s_barrier();
        asm volatile("" ::: "memory");
        __builtin_amdgcn_s_setprio(1);
#pragma unroll
        for (int fi = 0; fi < 2; fi++)
#pragma unroll
          for (int fj = 0; fj < 4; fj++) {
            acc[p * 2 + fi][fj] = mfma16(afr[fi][0], bfr[fj][0], acc[p * 2 + fi][fj]);
            acc[p * 2 + fi][fj] = mfma16(afr[fi][1], bfr[fj][1], acc[p * 2 + fi][fj]);
          }
        __builtin_amdgcn_s_setprio(0);
        // derived per-slot waits: each forces exactly the slots read in the
        // next two phases, keeps >=4 newest slots (8 loads) in flight
        if (p == 1) {
          if (half == 0) {
            if (m2) asm volatile("s_waitcnt vmcnt(10)" ::: "memory");
            else    asm volatile("s_waitcnt vmcnt(8)" ::: "memory");
          } else {
            if (m3) asm volatile("s_waitcnt vmcnt(10)" ::: "memory");
            else    asm volatile("s_waitcnt vmcnt(0)" ::: "memory");
          }
        } else if (p == 3) {
          if (half == 0) {
            if (m2) asm volatile("s_waitcnt vmcnt(8)" ::: "memory");
            else    asm volatile("s_waitcnt vmcnt(2)" ::: "memory");
          } else {
            if (m3) asm volatile("s_waitcnt vmcnt(8)" ::: "memory");
            else    asm volatile("s_waitcnt vmcnt(0)" ::: "memory");
          }
        }
        asm volatile("" ::: "memory");
        __builtin_amdgcn_s_barrier();
        asm volatile("" ::: "memory");
      }
    }
  }

  // ---------------- epilogue ----------------
  if (outQT) {
    if (n0 < 4096) {
      // q/k: per-wave LDS transpose bounce -> coalesced 16B stores.
      // wave-private 16KB region; layout [c 64][s 128] bf16 with 8B-slot
      // swizzle phys = slot ^ (c&6) (pair-preserving for b128 reads).
      unsigned short* trb = (wave < 4) ? (unsigned short*)&As[0][0] + wave * 8192
                                       : (unsigned short*)&Bs[0][0] + (wave - 4) * 8192;
#pragma unroll
      for (int j = 0; j < 4; j++) {
        const int c = j * 16 + l16;
        const float bv = bias ? bias[n0 + wn * 64 + c] : 0.f;
#pragma unroll
        for (int i = 0; i < 8; i++) {
          ushortx4 o;
          o.x = f32_bf16(acc[i][j][0] + bv);
          o.y = f32_bf16(acc[i][j][1] + bv);
          o.z = f32_bf16(acc[i][j][2] + bv);
          o.w = f32_bf16(acc[i][j][3] + bv);
          *(ushortx4*)&trb[c * 128 + (((i * 4 + quad) ^ (c & 6)) << 2)] = o;
        }
      }
      const int bb = m0 >> 11;
      const int sbase = (m0 & 2047) + wm * 128;
      unsigned short* tb = outQT + ((n0 & 2048) ? 16777216u : 0u);
      const int cg = lane >> 4;   // 0..3
      const int sl = lane & 15;   // covers s in 8-elem chunks
#pragma unroll
      for (int it = 0; it < 16; it++) {
        const int c = it * 4 + cg;
        ushortx8 v = *(const ushortx8*)&trb[c * 128 + (((2 * sl) ^ (c & 6)) << 2)];
        const int cc = (n0 + wn * 64 + c) & 2047;
        unsigned short* dst = tb +
            ((size_t)((bb << 4) + (cc >> 7)) * 128 + (cc & 127)) * 2048 + sbase + sl * 8;
        *(ushortx8*)dst = v;
      }
    } else {
      // V: direct store (row-major, 32B runs)
#pragma unroll
      for (int i = 0; i < 8; i++)
#pragma unroll
        for (int j = 0; j < 4; j++) {
          const int col = n0 + wn * 64 + j * 16 + l16;
          const float bv = bias ? bias[col] : 0.f;
#pragma unroll
          for (int r = 0; r < 4; r++) {
            const int row = m0 + wm * 128 + i * 16 + quad * 4 + r;
            outB[(size_t)row * 2048 + (col - 4096)] = f32_bf16(acc[i][j][r] + bv);
          }
        }
    }
    return;
  }

  float s1 = 0.f, s2 = 0.f;
#pragma unroll
  for (int i = 0; i < 8; i++) {
#pragma unroll
    for (int j = 0; j < 4; j++) {
      const int col = n0 + wn * 64 + j * 16 + l16;
      const float bv = bias ? bias[col] : 0.f;
#pragma unroll
      for (int r = 0; r < 4; r++) {
        const int row = m0 + wm * 128 + i * 16 + quad * 4 + r;
        float v = acc[i][j][r] + bv;
        if (doGelu) v = gelu_f(v);
        const size_t cidx = (size_t)row * ldc + col;
        if (residF) v += residF[cidx];
        if (residB) v += bf16_f32(residB[cidx]);
        if (accum) v += outF[cidx];
        if (outF) outF[cidx] = v;
        else outB[cidx] = f32_bf16(v);
        if (stats) { s1 += v; s2 += v * v; }
      }
    }
  }
  if (stats) {
#pragma unroll
    for (int off = 32; off; off >>= 1) {
      s1 += __shfl_down(s1, off);
      s2 += __shfl_down(s2, off);
    }
    if (lane == 0) {
      atomicAdd(&stats[0], s1);
      atomicAdd(&stats[1], s2);
    }
  }
}

// ---------------- launch ----------------
// Workspace (region lifetimes overlapped), base 152 MiB:
//   P0 32MiB: xbf -> attnbf -> hchunk(nc=4)
//   P1 24MiB: W1bf -> {spart 4x4MiB + probs(2) @ +16Mi} -> W2bf(8) -> {fc_ch+pj_ch} (nc=4)
//   P2 96MiB: {vbf(32)+qT(32)+kT(32)} -> {r12 fp32(64) + x1bf(32)}
//   P3 (optional, ws-adaptive): FFN fc/pj/h for nc=1 (192MiB) or nc=2 (96MiB)

extern "C" void kernel_launch(void* const* d_in, const int* in_sizes, int n_in, void* d_out,
                              int out_size, void* d_ws, size_t ws_size, hipStream_t stream) {
  (void)in_sizes; (void)n_in; (void)out_size;
  const float* x    = (const float*)d_in[0];
  const float* W1w  = (const float*)d_in[1];
  const float* W1b  = (const float*)d_in[2];
  const float* W2w  = (const float*)d_in[3];
  const float* W2b  = (const float*)d_in[4];
  const float* fcw  = (const float*)d_in[5];
  const float* fcb  = (const float*)d_in[6];
  const float* pjw  = (const float*)d_in[7];
  const float* pjb  = (const float*)d_in[8];
  const float* ln1w = (const float*)d_in[9];
  const float* ln1b = (const float*)d_in[10];
  const float* ln2w = (const float*)d_in[11];
  const float* ln2b = (const float*)d_in[12];
  float* out = (float*)d_out;

  char* ws = (char*)d_ws;
  size_t off = 0;
  auto take = [&](size_t b) { size_t r = off; off = (off + b + 255) & ~(size_t)255; return r; };
  float* stats = (float*)(ws + take(256));
  size_t P0 = take(33554432);
  size_t P1 = take(25165824);
  size_t P2 = take(100663296);
  size_t P3 = off;

  unsigned short* xbf    = (unsigned short*)(ws + P0);
  unsigned short* attnbf = (unsigned short*)(ws + P0);
  unsigned short* W1bf   = (unsigned short*)(ws + P1);
  float*          spart  = (float*)(ws + P1);                      // 4 partials x 4MiB
  unsigned short* probs  = (unsigned short*)(ws + P1 + 16777216);  // 2MiB
  unsigned short* W2bf   = (unsigned short*)(ws + P1);
  unsigned short* vbf    = (unsigned short*)(ws + P2);
  unsigned short* qT     = (unsigned short*)(ws + P2 + 33554432);  // kT = qT + 16Mi elems
  float*          r12    = (float*)(ws + P2);
  unsigned short* x1bf   = (unsigned short*)(ws + P2 + 67108864);

  // ws-adaptive FFN chunking
  int nc;
  unsigned short *fc_ch, *pj_ch, *hch;
  if (ws_size >= P3 + 201326592) {  // 192 MiB extra
    nc = 1;
    fc_ch = (unsigned short*)(ws + P3);
    pj_ch = (unsigned short*)(ws + P3 + 33554432);
    hch   = (unsigned short*)(ws + P3 + 67108864);
  } else if (ws_size >= P3 + 100663296) {  // 96 MiB extra
    nc = 2;
    fc_ch = (unsigned short*)(ws + P3);
    pj_ch = (unsigned short*)(ws + P3 + 16777216);
    hch   = (unsigned short*)(ws + P3 + 33554432);
  } else {
    nc = 4;
    fc_ch = (unsigned short*)(ws + P1);
    pj_ch = (unsigned short*)(ws + P1 + 8388608);
    hch   = (unsigned short*)(ws + P0);
  }
  const int cw = 8192 / nc;
  const int cwlog4 = (nc == 1) ? 11 : (nc == 2) ? 10 : 9;
  const long cn4 = (long)cw << 9;  // cw*2048/4

  zero_f<<<1, 64, 0, stream>>>(stats, 16);
  cvt_f32_bf16<<<16384, 256, 0, stream>>>(x, xbf, 4194304);
  cvt_f32_bf16<<<12288, 256, 0, stream>>>(W1w, W1bf, 3145728);

  // QKV: [8192,2048] @ [6144,2048]^T + W1_b -> qT/kT [b,h,128,2048] + vbf [8192,2048]
  gemm256<<<dim3(24, 32, 1), 512, 0, stream>>>(xbf, 2048, W1bf, 2048, 2048, W1b, nullptr,
                                               nullptr, 0, nullptr, vbf, qT, 0, 0, nullptr);
  // scores per (b,h), K split 4-way: qT[128,512-slice] @ kT^T -> 4 fp32 partials
  gemm_bt<<<dim3(1, 1, 256), 256, 0, stream>>>(qT, 2048, 262144L, 512L, qT + 16777216, 2048,
                                               262144L, 512L, 512, 4, nullptr, nullptr, nullptr,
                                               0, spart, nullptr, nullptr, 128, 16384L, 1048576L,
                                               0, nullptr);
  softmax_k<<<2048, 256, 0, stream>>>(spart, probs);
  // PV per (b,h): P[128,128] @ V[2048,128]^T -> attn2d[b, h*128+d, s] bf16
  gemm_bt<<<dim3(16, 1, 64), 256, 0, stream>>>(probs, 128, 262144L, 16384L, vbf, 2048, 4194304L,
                                               128L, 128, 16, nullptr, nullptr, nullptr, 0,
                                               nullptr, attnbf, nullptr, 2048, 4194304L, 262144L,
                                               0, nullptr);
  cvt_f32_bf16<<<4096, 256, 0, stream>>>(W2w, W2bf, 1048576);
  // W2 + bias + residual(x fp32) -> r1 fp32, stats[0:2]
  gemm256<<<dim3(8, 32, 1), 512, 0, stream>>>(attnbf, 2048, W2bf, 2048, 2048, W2b, x, nullptr,
                                              0, r12, nullptr, nullptr, 2048, 0, stats);
  ln_apply<<<16384, 256, 0, stream>>>(r12, stats, ln1w, ln1b, nullptr, x1bf, 4194304);

  // FFN in nc chunks of cw: h = gelu(x1 @ fc_ch^T + fcb_ch); r2 (+)= h @ pj_ch^T
  for (int c = 0; c < nc; ++c) {
    cvt_f32_bf16<<<(int)(cn4 / 256), 256, 0, stream>>>(fcw + (size_t)c * cw * 2048, fc_ch, cn4);
    cvt_cols<<<(int)(cn4 / 256), 256, 0, stream>>>(pjw, pj_ch, c * cw, cwlog4, cn4);
    gemm256<<<dim3(cw / 256, 32, 1), 512, 0, stream>>>(x1bf, 2048, fc_ch, 2048, 2048,
                                                       fcb + c * cw, nullptr, nullptr, 0,
                                                       nullptr, hch, nullptr, cw, 1, nullptr);
    const int last = (c == nc - 1);
    gemm256<<<dim3(8, 32, 1), 512, 0, stream>>>(hch, cw, pj_ch, cw, cw,
                                                last ? pjb : nullptr, nullptr,
                                                last ? x1bf : nullptr, c > 0, r12, nullptr,
                                                nullptr, 2048, 0,
                                                last ? (stats + 2) : nullptr);
  }
  ln_apply<<<16384, 256, 0, stream>>>(r12, stats + 2, ln2w, ln2b, out, nullptr, 4194304);
}

// Round 3
// 1342.140 us; speedup vs baseline: 1.2925x; 1.0025x over previous
//
#include <hip/hip_runtime.h>
#include <math.h>

typedef float floatx4 __attribute__((ext_vector_type(4)));
typedef __bf16 bf16x8 __attribute__((ext_vector_type(8)));
typedef unsigned short ushortx8 __attribute__((ext_vector_type(8)));
typedef unsigned short ushortx4 __attribute__((ext_vector_type(4)));
typedef unsigned short ushortx2 __attribute__((ext_vector_type(2)));

typedef unsigned int __attribute__((address_space(1))) as1_uint;
typedef unsigned int __attribute__((address_space(3))) as3_uint;

#define DEV static __device__ __forceinline__

DEV unsigned short f32_bf16(float f) {
  unsigned u = __float_as_uint(f);
  u += 0x7FFFu + ((u >> 16) & 1u);
  return (unsigned short)(u >> 16);
}
DEV float bf16_f32(unsigned short h) { return __uint_as_float(((unsigned)h) << 16); }
DEV float gelu_f(float x) {
  // 0.5x(1+tanh(t)) == x * sigmoid(2t); error vs tanhf ~1e-7 rel, << bf16 ulp
  float t2 = 1.5957691216057308f * (x + 0.044715f * x * x * x);
  return x * __builtin_amdgcn_rcpf(1.0f + __expf(-t2));
}
DEV void gload16(const void* g, void* l) {
  __builtin_amdgcn_global_load_lds((const as1_uint*)g, (as3_uint*)l, 16, 0, 0);
}
DEV floatx4 mfma16(ushortx8 a, ushortx8 b, floatx4 c) {
  return __builtin_amdgcn_mfma_f32_16x16x32_bf16(
      __builtin_bit_cast(bf16x8, a), __builtin_bit_cast(bf16x8, b), c, 0, 0, 0);
}

// ---------------- small kernels ----------------

__global__ void zero_f(float* p, int n) {
  int i = threadIdx.x;
  if (i < n) p[i] = 0.f;
}

__global__ void cvt_f32_bf16(const float* __restrict__ in, unsigned short* __restrict__ out,
                             long n4) {
  long i = (long)blockIdx.x * blockDim.x + threadIdx.x;
  if (i >= n4) return;
  float4 v = ((const float4*)in)[i];
  ushortx4 o;
  o.x = f32_bf16(v.x); o.y = f32_bf16(v.y); o.z = f32_bf16(v.z); o.w = f32_bf16(v.w);
  ((ushortx4*)out)[i] = o;
}

// out[n*cw + k] = in[n*8192 + cbase + k], n<2048, k<cw ; cwlog4 = log2(cw/4)
__global__ void cvt_cols(const float* __restrict__ in, unsigned short* __restrict__ out,
                         int cbase, int cwlog4, long n4) {
  long i = (long)blockIdx.x * blockDim.x + threadIdx.x;
  if (i >= n4) return;
  int n = (int)(i >> cwlog4);
  int k4 = (int)(i & ((1 << cwlog4) - 1)) << 2;
  float4 v = *(const float4*)&in[(size_t)n * 8192 + cbase + k4];
  ushortx4 o;
  o.x = f32_bf16(v.x); o.y = f32_bf16(v.y); o.z = f32_bf16(v.z); o.w = f32_bf16(v.w);
  *(ushortx4*)&out[((size_t)n << (cwlog4 + 2)) + k4] = o;
}

// one wave per (bh,d) row of 128; sums 4 K-split partials (stride 1Mi floats),
// scale by 1/sqrt(S), softmax, bf16 out
__global__ __launch_bounds__(256) void softmax_k(const float* __restrict__ sc,
                                                 unsigned short* __restrict__ probs) {
  int r = blockIdx.x * 4 + (threadIdx.x >> 6);
  int lane = threadIdx.x & 63;
  size_t base = (size_t)(r >> 7) * 16384 + (size_t)(r & 127) * 128 + lane * 2;
  float2 p0 = *(const float2*)&sc[base];
  float2 p1 = *(const float2*)&sc[base + 1048576];
  float2 p2 = *(const float2*)&sc[base + 2097152];
  float2 p3 = *(const float2*)&sc[base + 3145728];
  const float scale = 0.022097086912079608f;  // 1/sqrt(2048)
  float vx = (p0.x + p1.x + p2.x + p3.x) * scale;
  float vy = (p0.y + p1.y + p2.y + p3.y) * scale;
  float m = fmaxf(vx, vy);
#pragma unroll
  for (int off = 32; off; off >>= 1) m = fmaxf(m, __shfl_xor(m, off));
  float ex = expf(vx - m), ey = expf(vy - m);
  float s = ex + ey;
#pragma unroll
  for (int off = 32; off; off >>= 1) s += __shfl_xor(s, off);
  float inv = 1.f / s;
  ushortx2 o;
  o.x = f32_bf16(ex * inv);
  o.y = f32_bf16(ey * inv);
  *(ushortx2*)&probs[base] = o;
}

// global layernorm apply: out = (r - mean)*rstd*w[col] + b[col]
__global__ void ln_apply(const float* __restrict__ r, const float* __restrict__ stats,
                         const float* __restrict__ w, const float* __restrict__ bia,
                         float* __restrict__ outF, unsigned short* __restrict__ outB, long n4) {
  long i = (long)blockIdx.x * blockDim.x + threadIdx.x;
  if (i >= n4) return;
  const double total = 16777216.0;
  double mean = (double)stats[0] / total;
  double var = ((double)stats[1] - total * mean * mean) / (total - 1.0);
  float rstd = (float)(1.0 / sqrt(var + 1e-12));
  float fm = (float)mean;
  int col = (int)((i * 4) & 2047);
  float4 v = ((const float4*)r)[i];
  float4 wv = *(const float4*)&w[col];
  float4 bv = *(const float4*)&bia[col];
  float4 o;
  o.x = (v.x - fm) * rstd * wv.x + bv.x;
  o.y = (v.y - fm) * rstd * wv.y + bv.y;
  o.z = (v.z - fm) * rstd * wv.z + bv.z;
  o.w = (v.w - fm) * rstd * wv.w + bv.w;
  if (outF) ((float4*)outF)[i] = o;
  if (outB) {
    ushortx4 ob;
    ob.x = f32_bf16(o.x); ob.y = f32_bf16(o.y); ob.z = f32_bf16(o.z); ob.w = f32_bf16(o.w);
    ((ushortx4*)outB)[i] = ob;
  }
}

// ---------------- 128-tile GEMM (kept for scores / PV, z-sliced) ----------------
__global__ __launch_bounds__(256) void gemm_bt(
    const unsigned short* __restrict__ A, int lda, long sAo, long sAi,
    const unsigned short* __restrict__ B, int ldb, long sBo, long sBi,
    int K, int innerCnt,
    const float* __restrict__ bias, const float* __restrict__ residF,
    const unsigned short* __restrict__ residB, int accum,
    float* __restrict__ outF, unsigned short* __restrict__ outB,
    unsigned short* __restrict__ outQT,
    int ldc, long sCo, long sCi, int doGelu, float* __restrict__ stats) {
  __shared__ unsigned short As[128 * 64];
  __shared__ unsigned short Bs[128 * 64];
  const int tid = threadIdx.x;
  const int wave = tid >> 6;
  const int lane = tid & 63;
  const int z = blockIdx.z;
  const int zo = z / innerCnt, zi = z % innerCnt;
  const unsigned short* Ab = A + zo * sAo + zi * sAi;
  const unsigned short* Bb = B + zo * sBo + zi * sBi;
  const long coff = zo * sCo + zi * sCi;
  const int m0 = blockIdx.y * 128;
  const int n0 = blockIdx.x * 128;

  const int quad = lane >> 4;
  const int l16 = lane & 15;
  const int wm = (wave & 1) * 64;
  const int wn = (wave >> 1) * 64;
  const int srow = lane >> 3;
  const int kofs8 = (((lane & 7) ^ srow) & 7) * 8;

  floatx4 acc[4][4];
#pragma unroll
  for (int i = 0; i < 4; i++)
#pragma unroll
    for (int j = 0; j < 4; j++) acc[i][j] = (floatx4){0.f, 0.f, 0.f, 0.f};

  const int nK = K >> 6;
  for (int kt = 0; kt < nK; ++kt) {
    const int k0 = kt << 6;
    __syncthreads();
#pragma unroll
    for (int i = 0; i < 4; ++i) {
      const int rb = wave * 32 + i * 8;
      gload16(Ab + (size_t)(m0 + rb + srow) * lda + k0 + kofs8, &As[rb * 64]);
      gload16(Bb + (size_t)(n0 + rb + srow) * ldb + k0 + kofs8, &Bs[rb * 64]);
    }
    __syncthreads();
#pragma unroll
    for (int kk = 0; kk < 2; ++kk) {
      ushortx8 af[4], bf[4];
      const int swz = (l16 & 7);
#pragma unroll
      for (int i = 0; i < 4; i++)
        af[i] = *(const ushortx8*)&As[(wm + i * 16 + l16) * 64 +
                                      (((kk * 4 + quad) ^ swz) * 8)];
#pragma unroll
      for (int j = 0; j < 4; j++)
        bf[j] = *(const ushortx8*)&Bs[(wn + j * 16 + l16) * 64 +
                                      (((kk * 4 + quad) ^ swz) * 8)];
#pragma unroll
      for (int i = 0; i < 4; i++)
#pragma unroll
        for (int j = 0; j < 4; j++) acc[i][j] = mfma16(af[i], bf[j], acc[i][j]);
    }
  }

  float s1 = 0.f, s2 = 0.f;
#pragma unroll
  for (int i = 0; i < 4; i++) {
#pragma unroll
    for (int j = 0; j < 4; j++) {
      const int col = n0 + wn + j * 16 + l16;
      const float bv = bias ? bias[col] : 0.f;
#pragma unroll
      for (int r = 0; r < 4; r++) {
        const int row = m0 + wm + i * 16 + quad * 4 + r;
        float v = acc[i][j][r] + bv;
        if (doGelu) v = gelu_f(v);
        if (outQT) {
          const int b = row >> 11, s = row & 2047;
          if (col < 4096) {
            unsigned short* tb = outQT + ((col & 2048) ? 16777216u : 0u);
            const int cc = col & 2047;
            tb[((size_t)((b << 4) + (cc >> 7)) * 128 + (cc & 127)) * 2048 + s] = f32_bf16(v);
          } else {
            outB[(size_t)row * 2048 + (col - 4096)] = f32_bf16(v);
          }
          continue;
        }
        const size_t cidx = (size_t)coff + (size_t)row * ldc + col;
        if (residF) v += residF[cidx];
        if (residB) v += bf16_f32(residB[cidx]);
        if (accum) v += outF[cidx];
        if (outF) outF[cidx] = v;
        else outB[cidx] = f32_bf16(v);
        if (stats) { s1 += v; s2 += v * v; }
      }
    }
  }
  if (stats) {
#pragma unroll
    for (int off = 32; off; off >>= 1) {
      s1 += __shfl_down(s1, off);
      s2 += __shfl_down(s2, off);
    }
    if (lane == 0) {
      atomicAdd(&stats[0], s1);
      atomicAdd(&stats[1], s2);
    }
  }
}

// ---------------- 256x256 8-phase GEMM (T1+T2+T3+T4+T5) ----------------
// Round-3 change: STATIC double-buffering. Four separate __shared__ arrays
// (As0/As1/Bs0/Bs1) and compile-time buffer selection for every
// global_load_lds (loop body unrolled over tile parity). Round-2 used
// As[2][...] with runtime buf=kt&1 -> the backend's waitcnt pass cannot
// prove ds_read vs in-flight global_load_lds disjointness and inserts a
// conservative s_waitcnt vmcnt(0) before reads, draining the pipeline
// every phase (measured: 2213 cy/phase vs ~824 expected; MfmaUtil 23.5%).
// With named arrays, every phase's ds_reads target a different array than
// all possibly-outstanding staged writes (schedule audited below), so only
// our counted waits remain.
// Per phase: {ds_read subtile; stage ONE 16KB slot; [lgkmcnt(8) if 12 reads];
// s_barrier; lgkmcnt(0)+sched_barrier; setprio(1); 16 MFMA; setprio(0);
// [p3 only: vmcnt(6), tail vmcnt(0)]; s_barrier}.  Requires K%128==0.
__global__ __launch_bounds__(512, 2) void gemm256(
    const unsigned short* __restrict__ A, int lda,
    const unsigned short* __restrict__ B, int ldb, int K,
    const float* __restrict__ bias, const float* __restrict__ residF,
    const unsigned short* __restrict__ residB, int accum,
    float* __restrict__ outF, unsigned short* __restrict__ outB,
    unsigned short* __restrict__ outQT, int ldc, int doGelu,
    float* __restrict__ stats) {
  __shared__ unsigned short As0[256 * 64];
  __shared__ unsigned short As1[256 * 64];
  __shared__ unsigned short Bs0[256 * 64];
  __shared__ unsigned short Bs1[256 * 64];
  const int tid = threadIdx.x;
  const int wave = tid >> 6;     // 0..7
  const int lane = tid & 63;
  const int wm = wave >> 2;      // 0..1  (M)
  const int wn = wave & 3;       // 0..3  (N)
  const int quad = lane >> 4;
  const int l16 = lane & 15;
  const int swz = l16 & 7;

  // bijective XCD-chunked swizzle (m204) + rectangular intra-XCD mapping
  const int nwg = gridDim.x * gridDim.y;
  const int orig = blockIdx.y * gridDim.x + blockIdx.x;
  const int q8 = nwg >> 3, r8 = nwg & 7;
  const int xcd = orig & 7, lid = orig >> 3;
  const int wgid = (xcd < r8 ? xcd * (q8 + 1) : r8 * (q8 + 1) + (xcd - r8) * q8) + lid;
  int m0, n0;
  if ((gridDim.x & 7) == 0) {
    const int gper = (int)(gridDim.y << 3);
    m0 = ((wgid % gper) >> 3) * 256;
    n0 = (((wgid / gper) << 3) + (wgid & 7)) * 256;
  } else {
    m0 = (wgid / gridDim.x) * 256;
    n0 = (wgid % gridDim.x) * 256;
  }

  const int srow = lane >> 3;
  const int kof = (((lane & 7) ^ srow) & 7) << 3;  // pre-swizzled global k-offset
  const int nkt = K >> 6;                          // even, >= 2

  floatx4 acc[8][4];
#pragma unroll
  for (int i = 0; i < 8; i++)
#pragma unroll
    for (int j = 0; j < 4; j++) acc[i][j] = (floatx4){0.f, 0.f, 0.f, 0.f};

  // stage one 16KB slot of K-tile kt (2 gload16/thread), dst buffer STATIC.
  // B slots: s=0 rows[0,128) s=1 rows[128,256). A slots: hi=0 rows
  // [0,64)+[128,192), hi=1 rows [64,128)+[192,256).
  auto stageB = [&](unsigned short* dst, int kt, int s) {
    const int k0 = kt << 6;
    const int rb = s * 128 + wave * 16;
    gload16(B + (size_t)(n0 + rb + srow) * ldb + k0 + kof, &dst[rb * 64]);
    gload16(B + (size_t)(n0 + rb + 8 + srow) * ldb + k0 + kof, &dst[(rb + 8) * 64]);
  };
  auto stageA = [&](unsigned short* dst, int kt, int hi) {
    const int k0 = kt << 6;
    const int rb = ((wave & 4) << 5) + ((wave & 3) << 4) + hi * 64;
    gload16(A + (size_t)(m0 + rb + srow) * lda + k0 + kof, &dst[rb * 64]);
    gload16(A + (size_t)(m0 + rb + 8 + srow) * lda + k0 + kof, &dst[(rb + 8) * 64]);
  };

  ushortx8 bfr[4][2], afr[2][2];
  const int aBase = (wm * 128 + l16) * 64;
  const int bBase = (wn * 64 + l16) * 64;
  const int kq0 = (quad ^ swz) << 3;
  const int kq1 = ((4 + quad) ^ swz) << 3;

  auto rdB = [&](const unsigned short* Bsb) {
#pragma unroll
    for (int fj = 0; fj < 4; fj++) {
      bfr[fj][0] = *(const ushortx8*)&Bsb[bBase + fj * 1024 + kq0];
      bfr[fj][1] = *(const ushortx8*)&Bsb[bBase + fj * 1024 + kq1];
    }
  };
  auto rdA = [&](const unsigned short* Asb, int p) {
#pragma unroll
    for (int fi = 0; fi < 2; fi++) {
      afr[fi][0] = *(const ushortx8*)&Asb[aBase + (p * 2 + fi) * 1024 + kq0];
      afr[fi][1] = *(const ushortx8*)&Asb[aBase + (p * 2 + fi) * 1024 + kq1];
    }
  };
  auto mma = [&](int p) {
    __builtin_amdgcn_s_setprio(1);
#pragma unroll
    for (int fi = 0; fi < 2; fi++)
#pragma unroll
      for (int fj = 0; fj < 4; fj++) {
        acc[p * 2 + fi][fj] = mfma16(afr[fi][0], bfr[fj][0], acc[p * 2 + fi][fj]);
        acc[p * 2 + fi][fj] = mfma16(afr[fi][1], bfr[fj][1], acc[p * 2 + fi][fj]);
      }
    __builtin_amdgcn_s_setprio(0);
  };

#define BAR() __builtin_amdgcn_s_barrier()
#define LGKM0()                                            \
  do {                                                     \
    asm volatile("s_waitcnt lgkmcnt(0)" ::: "memory");     \
    __builtin_amdgcn_sched_barrier(0);                     \
  } while (0)
#define LGKM8() asm volatile("s_waitcnt lgkmcnt(8)" ::: "memory")
#define VM6() asm volatile("s_waitcnt vmcnt(6)" ::: "memory")
#define VM0() asm volatile("s_waitcnt vmcnt(0)" ::: "memory")

  // prologue: tile0 fully + tile1 B0,B1,A-hi0 (7 slots = 14 loads in flight)
  stageB(Bs0, 0, 0); stageB(Bs0, 0, 1); stageA(As0, 0, 0); stageA(As0, 0, 1);
  if (nkt > 1) { stageB(Bs1, 1, 0); stageB(Bs1, 1, 1); stageA(As1, 1, 0); }
  VM6();  // tile0 landed; t1{B0,B1,Ahi0} in flight
  BAR();

  // staging order per iteration (parities static):
  //  h0p0: t(kt+1) A-hi1 -> As1 | h0p1: t(kt+2) B0 -> Bs0
  //  h0p2: t(kt+2) B1 -> Bs0    | h0p3: t(kt+2) A-hi0 -> As0
  //  h1p0: t(kt+2) A-hi1 -> As0 | h1p1: t(kt+3) B0 -> Bs1
  //  h1p2: t(kt+3) B1 -> Bs1    | h1p3: t(kt+3) A-hi0 -> As1
  // h0p3 VM6 -> forces t(kt+1) complete; h1p3 VM6 -> forces t(kt+2).
  for (int kt = 0; kt < nkt; kt += 2) {
    const bool t2 = kt + 2 < nkt, t3 = kt + 3 < nkt;
    // ---- half 0: tile kt from As0/Bs0 ----
    rdB(Bs0); rdA(As0, 0);
    if (kt + 1 < nkt) stageA(As1, kt + 1, 1);
    LGKM8();
    BAR(); LGKM0(); mma(0); BAR();

    rdA(As0, 1); if (t2) stageB(Bs0, kt + 2, 0);
    BAR(); LGKM0(); mma(1); BAR();

    rdA(As0, 2); if (t2) stageB(Bs0, kt + 2, 1);
    BAR(); LGKM0(); mma(2); BAR();

    rdA(As0, 3); if (t2) stageA(As0, kt + 2, 0);
    BAR(); LGKM0(); mma(3);
    if (t2) VM6(); else VM0();
    BAR();

    // ---- half 1: tile kt+1 from As1/Bs1 ----
    rdB(Bs1); rdA(As1, 0);
    if (t2) stageA(As0, kt + 2, 1);
    LGKM8();
    BAR(); LGKM0(); mma(0); BAR();

    rdA(As1, 1); if (t3) stageB(Bs1, kt + 3, 0);
    BAR(); LGKM0(); mma(1); BAR();

    rdA(As1, 2); if (t3) stageB(Bs1, kt + 3, 1);
    BAR(); LGKM0(); mma(2); BAR();

    rdA(As1, 3); if (t3) stageA(As1, kt + 3, 0);
    BAR(); LGKM0(); mma(3);
    if (t3) VM6();
    BAR();
  }
#undef BAR
#undef LGKM0
#undef LGKM8
#undef VM6
#undef VM0

  // ---------------- epilogue ----------------
  if (outQT) {
    if (n0 < 4096) {
      // q/k: per-wave LDS transpose bounce -> coalesced 16B stores.
      // wave-private 16KB region; layout [c 64][s 128] bf16 with 8B-slot
      // swizzle phys = slot ^ (c&6) (pair-preserving for b128 reads).
      unsigned short* trb = (wave < 4) ? As0 + wave * 8192 : Bs0 + (wave - 4) * 8192;
#pragma unroll
      for (int j = 0; j < 4; j++) {
        const int c = j * 16 + l16;
        const float bv = bias ? bias[n0 + wn * 64 + c] : 0.f;
#pragma unroll
        for (int i = 0; i < 8; i++) {
          ushortx4 o;
          o.x = f32_bf16(acc[i][j][0] + bv);
          o.y = f32_bf16(acc[i][j][1] + bv);
          o.z = f32_bf16(acc[i][j][2] + bv);
          o.w = f32_bf16(acc[i][j][3] + bv);
          *(ushortx4*)&trb[c * 128 + (((i * 4 + quad) ^ (c & 6)) << 2)] = o;
        }
      }
      const int bb = m0 >> 11;
      const int sbase = (m0 & 2047) + wm * 128;
      unsigned short* tb = outQT + ((n0 & 2048) ? 16777216u : 0u);
      const int cg = lane >> 4;   // 0..3
      const int sl = lane & 15;   // covers s in 8-elem chunks
#pragma unroll
      for (int it = 0; it < 16; it++) {
        const int c = it * 4 + cg;
        ushortx8 v = *(const ushortx8*)&trb[c * 128 + (((2 * sl) ^ (c & 6)) << 2)];
        const int cc = (n0 + wn * 64 + c) & 2047;
        unsigned short* dst = tb +
            ((size_t)((bb << 4) + (cc >> 7)) * 128 + (cc & 127)) * 2048 + sbase + sl * 8;
        *(ushortx8*)dst = v;
      }
    } else {
      // V: direct store (row-major, 32B runs)
#pragma unroll
      for (int i = 0; i < 8; i++)
#pragma unroll
        for (int j = 0; j < 4; j++) {
          const int col = n0 + wn * 64 + j * 16 + l16;
          const float bv = bias ? bias[col] : 0.f;
#pragma unroll
          for (int r = 0; r < 4; r++) {
            const int row = m0 + wm * 128 + i * 16 + quad * 4 + r;
            outB[(size_t)row * 2048 + (col - 4096)] = f32_bf16(acc[i][j][r] + bv);
          }
        }
    }
    return;
  }

  float s1 = 0.f, s2 = 0.f;
#pragma unroll
  for (int i = 0; i < 8; i++) {
#pragma unroll
    for (int j = 0; j < 4; j++) {
      const int col = n0 + wn * 64 + j * 16 + l16;
      const float bv = bias ? bias[col] : 0.f;
#pragma unroll
      for (int r = 0; r < 4; r++) {
        const int row = m0 + wm * 128 + i * 16 + quad * 4 + r;
        float v = acc[i][j][r] + bv;
        if (doGelu) v = gelu_f(v);
        const size_t cidx = (size_t)row * ldc + col;
        if (residF) v += residF[cidx];
        if (residB) v += bf16_f32(residB[cidx]);
        if (accum) v += outF[cidx];
        if (outF) outF[cidx] = v;
        else outB[cidx] = f32_bf16(v);
        if (stats) { s1 += v; s2 += v * v; }
      }
    }
  }
  if (stats) {
#pragma unroll
    for (int off = 32; off; off >>= 1) {
      s1 += __shfl_down(s1, off);
      s2 += __shfl_down(s2, off);
    }
    if (lane == 0) {
      atomicAdd(&stats[0], s1);
      atomicAdd(&stats[1], s2);
    }
  }
}

// ---------------- launch ----------------
// Workspace (region lifetimes overlapped), base 152 MiB:
//   P0 32MiB: xbf -> attnbf -> hchunk(nc=4)
//   P1 24MiB: W1bf -> {spart 4x4MiB + probs(2) @ +16Mi} -> W2bf(8) -> {fc_ch+pj_ch} (nc=4)
//   P2 96MiB: {vbf(32)+qT(32)+kT(32)} -> {r12 fp32(64) + x1bf(32)}
//   P3 (optional, ws-adaptive): FFN fc/pj/h for nc=1 (192MiB) or nc=2 (96MiB)

extern "C" void kernel_launch(void* const* d_in, const int* in_sizes, int n_in, void* d_out,
                              int out_size, void* d_ws, size_t ws_size, hipStream_t stream) {
  (void)in_sizes; (void)n_in; (void)out_size;
  const float* x    = (const float*)d_in[0];
  const float* W1w  = (const float*)d_in[1];
  const float* W1b  = (const float*)d_in[2];
  const float* W2w  = (const float*)d_in[3];
  const float* W2b  = (const float*)d_in[4];
  const float* fcw  = (const float*)d_in[5];
  const float* fcb  = (const float*)d_in[6];
  const float* pjw  = (const float*)d_in[7];
  const float* pjb  = (const float*)d_in[8];
  const float* ln1w = (const float*)d_in[9];
  const float* ln1b = (const float*)d_in[10];
  const float* ln2w = (const float*)d_in[11];
  const float* ln2b = (const float*)d_in[12];
  float* out = (float*)d_out;

  char* ws = (char*)d_ws;
  size_t off = 0;
  auto take = [&](size_t b) { size_t r = off; off = (off + b + 255) & ~(size_t)255; return r; };
  float* stats = (float*)(ws + take(256));
  size_t P0 = take(33554432);
  size_t P1 = take(25165824);
  size_t P2 = take(100663296);
  size_t P3 = off;

  unsigned short* xbf    = (unsigned short*)(ws + P0);
  unsigned short* attnbf = (unsigned short*)(ws + P0);
  unsigned short* W1bf   = (unsigned short*)(ws + P1);
  float*          spart  = (float*)(ws + P1);                      // 4 partials x 4MiB
  unsigned short* probs  = (unsigned short*)(ws + P1 + 16777216);  // 2MiB
  unsigned short* W2bf   = (unsigned short*)(ws + P1);
  unsigned short* vbf    = (unsigned short*)(ws + P2);
  unsigned short* qT     = (unsigned short*)(ws + P2 + 33554432);  // kT = qT + 16Mi elems
  float*          r12    = (float*)(ws + P2);
  unsigned short* x1bf   = (unsigned short*)(ws + P2 + 67108864);

  // ws-adaptive FFN chunking
  int nc;
  unsigned short *fc_ch, *pj_ch, *hch;
  if (ws_size >= P3 + 201326592) {  // 192 MiB extra
    nc = 1;
    fc_ch = (unsigned short*)(ws + P3);
    pj_ch = (unsigned short*)(ws + P3 + 33554432);
    hch   = (unsigned short*)(ws + P3 + 67108864);
  } else if (ws_size >= P3 + 100663296) {  // 96 MiB extra
    nc = 2;
    fc_ch = (unsigned short*)(ws + P3);
    pj_ch = (unsigned short*)(ws + P3 + 16777216);
    hch   = (unsigned short*)(ws + P3 + 33554432);
  } else {
    nc = 4;
    fc_ch = (unsigned short*)(ws + P1);
    pj_ch = (unsigned short*)(ws + P1 + 8388608);
    hch   = (unsigned short*)(ws + P0);
  }
  const int cw = 8192 / nc;
  const int cwlog4 = (nc == 1) ? 11 : (nc == 2) ? 10 : 9;
  const long cn4 = (long)cw << 9;  // cw*2048/4

  zero_f<<<1, 64, 0, stream>>>(stats, 16);
  cvt_f32_bf16<<<16384, 256, 0, stream>>>(x, xbf, 4194304);
  cvt_f32_bf16<<<12288, 256, 0, stream>>>(W1w, W1bf, 3145728);

  // QKV: [8192,2048] @ [6144,2048]^T + W1_b -> qT/kT [b,h,128,2048] + vbf [8192,2048]
  gemm256<<<dim3(24, 32, 1), 512, 0, stream>>>(xbf, 2048, W1bf, 2048, 2048, W1b, nullptr,
                                               nullptr, 0, nullptr, vbf, qT, 0, 0, nullptr);
  // scores per (b,h), K split 4-way: qT[128,512-slice] @ kT^T -> 4 fp32 partials
  gemm_bt<<<dim3(1, 1, 256), 256, 0, stream>>>(qT, 2048, 262144L, 512L, qT + 16777216, 2048,
                                               262144L, 512L, 512, 4, nullptr, nullptr, nullptr,
                                               0, spart, nullptr, nullptr, 128, 16384L, 1048576L,
                                               0, nullptr);
  softmax_k<<<2048, 256, 0, stream>>>(spart, probs);
  // PV per (b,h): P[128,128] @ V[2048,128]^T -> attn2d[b, h*128+d, s] bf16
  gemm_bt<<<dim3(16, 1, 64), 256, 0, stream>>>(probs, 128, 262144L, 16384L, vbf, 2048, 4194304L,
                                               128L, 128, 16, nullptr, nullptr, nullptr, 0,
                                               nullptr, attnbf, nullptr, 2048, 4194304L, 262144L,
                                               0, nullptr);
  cvt_f32_bf16<<<4096, 256, 0, stream>>>(W2w, W2bf, 1048576);
  // W2 + bias + residual(x fp32) -> r1 fp32, stats[0:2]
  gemm256<<<dim3(8, 32, 1), 512, 0, stream>>>(attnbf, 2048, W2bf, 2048, 2048, W2b, x, nullptr,
                                              0, r12, nullptr, nullptr, 2048, 0, stats);
  ln_apply<<<16384, 256, 0, stream>>>(r12, stats, ln1w, ln1b, nullptr, x1bf, 4194304);

  // FFN in nc chunks of cw: h = gelu(x1 @ fc_ch^T + fcb_ch); r2 (+)= h @ pj_ch^T
  for (int c = 0; c < nc; ++c) {
    cvt_f32_bf16<<<(int)(cn4 / 256), 256, 0, stream>>>(fcw + (size_t)c * cw * 2048, fc_ch, cn4);
    cvt_cols<<<(int)(cn4 / 256), 256, 0, stream>>>(pjw, pj_ch, c * cw, cwlog4, cn4);
    gemm256<<<dim3(cw / 256, 32, 1), 512, 0, stream>>>(x1bf, 2048, fc_ch, 2048, 2048,
                                                       fcb + c * cw, nullptr, nullptr, 0,
                                                       nullptr, hch, nullptr, cw, 1, nullptr);
    const int last = (c == nc - 1);
    gemm256<<<dim3(8, 32, 1), 512, 0, stream>>>(hch, cw, pj_ch, cw, cw,
                                                last ? pjb : nullptr, nullptr,
                                                last ? x1bf : nullptr, c > 0, r12, nullptr,
                                                nullptr, 2048, 0,
                                                last ? (stats + 2) : nullptr);
  }
  ln_apply<<<16384, 256, 0, stream>>>(r12, stats + 2, ln2w, ln2b, out, nullptr, 4194304);
}